// Round 1
// baseline (3625.703 us; speedup 1.0000x reference)
//
#include <hip/hip_runtime.h>

// NGCF forward on gfx950.
// Structure per call:
//   cur  = concat(user_emb, item_emb)            [150000 x 64] f32 (ws)
//   nbuf = segment-sum scratch                    [150000 x 64] f32 (ws)
//   gather layer-0 slice of out
//   for L in 0..2:
//     nbuf = 0; spmm_atomic: nbuf[rows] += vals * cur[cols]
//     transform_inplace: cur = leaky(cur@W1+b1 + t + (t*cur)@W2+b2), t = nbuf@W2+b2
//     gather layer-(L+1) slice of out
// out = [users_emb | pos_emb | neg_emb], each [16384 x 256] f32.

#define EMB 64

constexpr int kNUsers = 100000;
constexpr int kNItems = 50000;
constexpr int kNNodes = 150000;
constexpr int kNEdges = 4800000;
constexpr int kBatch  = 16384;
constexpr int kLayers = 3;
constexpr int kEPW    = 16;   // edges per wave in spmm

__device__ __forceinline__ float f4c(const float4& v, int i) {
  return ((const float*)&v)[i];   // i is always a compile-time constant after unroll
}
__device__ __forceinline__ float4 f4fma(float s, float4 w, float4 a) {
  a.x = fmaf(s, w.x, a.x);
  a.y = fmaf(s, w.y, a.y);
  a.z = fmaf(s, w.z, a.z);
  a.w = fmaf(s, w.w, a.w);
  return a;
}
__device__ __forceinline__ float lrelu(float x) { return x > 0.f ? x : 0.2f * x; }

// ---------------------------------------------------------------------------
// SpMM scatter: one wave handles kEPW edges; lane = embedding dim.
// Edge indices are wave-uniform -> scalar loads; feature read is a coalesced
// 256B gather; scatter is 64 fp32 atomics per edge.
// ---------------------------------------------------------------------------
__global__ __launch_bounds__(256) void spmm_atomic(
    const float* __restrict__ cur,
    const int* __restrict__ rows,
    const int* __restrict__ cols,
    const float* __restrict__ vals,
    float* __restrict__ nbuf)
{
  const int lane = threadIdx.x & 63;
  int wv = (blockIdx.x << 2) | (threadIdx.x >> 6);
  wv = __builtin_amdgcn_readfirstlane(wv);   // guarantee SGPR edge index base
  int e0 = wv * kEPW;
  int e1 = e0 + kEPW;
  if (e1 > kNEdges) e1 = kNEdges;
  for (int e = e0; e < e1; ++e) {
    const int   c = cols[e];
    const int   r = rows[e];
    const float v = vals[e];
    const float x = cur[(size_t)c * EMB + lane];
    atomicAdd(nbuf + (size_t)r * EMB + lane, v * x);
  }
}

// ---------------------------------------------------------------------------
// Fused per-node transform, in place on `cur`.
// Thread <-> node. acc1[16]/acc2[16] float4 = 128 VGPRs of accumulators.
// Weights indexed lane-invariantly -> s_load; FMAs are v_fmac(v, sgpr).
//   acc1 = b1 + x@W1          (self)
//   acc2 = b2 + nb@W2         (t)
//   acc1 += (t*x)@W2          (inter, pass fully unrolled so acc2[k] is static)
//   cur  = leaky(acc1 + acc2 + b2)
// ---------------------------------------------------------------------------
__global__ __launch_bounds__(256) void transform_inplace(
    float* __restrict__ cur, const float* __restrict__ nbuf,
    const float* __restrict__ W1, const float* __restrict__ b1,
    const float* __restrict__ W2, const float* __restrict__ b2)
{
  const int node = blockIdx.x * 256 + threadIdx.x;
  if (node >= kNNodes) return;

  const float4* __restrict__ xr  = (const float4*)(cur  + (size_t)node * EMB);
  const float4* __restrict__ nr  = (const float4*)(nbuf + (size_t)node * EMB);
  const float4* __restrict__ b1v = (const float4*)b1;
  const float4* __restrict__ b2v = (const float4*)b2;

  float4 acc1[16], acc2[16];
#pragma unroll
  for (int j = 0; j < 16; ++j) { acc1[j] = b1v[j]; acc2[j] = b2v[j]; }

  // pass 1+2: x@W1 and nb@W2, k-loop rolled (unroll 2) to bound code size
#pragma unroll 2
  for (int k4 = 0; k4 < 16; ++k4) {
    const float4 xv = xr[k4];
    const float4 nv = nr[k4];
#pragma unroll
    for (int kk = 0; kk < 4; ++kk) {
      const int k = 4 * k4 + kk;
      const float xs = f4c(xv, kk);
      const float ns = f4c(nv, kk);
      const float4* __restrict__ w1r = (const float4*)(W1 + k * EMB);
      const float4* __restrict__ w2r = (const float4*)(W2 + k * EMB);
#pragma unroll
      for (int j = 0; j < 16; ++j) {
        acc1[j] = f4fma(xs, w1r[j], acc1[j]);
        acc2[j] = f4fma(ns, w2r[j], acc2[j]);
      }
    }
  }

  // pass 3: inter = (t * x) @ W2, fully unrolled so acc2[k4] is a static index
#pragma unroll
  for (int k4 = 0; k4 < 16; ++k4) {
    const float4 xv = xr[k4];   // L1-hot reload
    const float4 tv = acc2[k4];
#pragma unroll
    for (int kk = 0; kk < 4; ++kk) {
      const float ms = f4c(tv, kk) * f4c(xv, kk);
      const float4* __restrict__ w2r = (const float4*)(W2 + (4 * k4 + kk) * EMB);
#pragma unroll
      for (int j = 0; j < 16; ++j) acc1[j] = f4fma(ms, w2r[j], acc1[j]);
    }
  }

  float4* __restrict__ outp = (float4*)(cur + (size_t)node * EMB);
#pragma unroll
  for (int j = 0; j < 16; ++j) {
    float4 r;
    r.x = lrelu(acc1[j].x + acc2[j].x + b2v[j].x);
    r.y = lrelu(acc1[j].y + acc2[j].y + b2v[j].y);
    r.z = lrelu(acc1[j].z + acc2[j].z + b2v[j].z);
    r.w = lrelu(acc1[j].w + acc2[j].w + b2v[j].w);
    outp[j] = r;
  }
}

// ---------------------------------------------------------------------------
// Gather one 64-wide layer slice into the [3*16384 x 256] output.
// Wave per output row, lane = dim.
// ---------------------------------------------------------------------------
__global__ __launch_bounds__(256) void gather_out(
    const float* __restrict__ cur,
    const int* __restrict__ users,
    const int* __restrict__ pos,
    const int* __restrict__ neg,
    float* __restrict__ out, int layer)
{
  const int t    = blockIdx.x * 256 + threadIdx.x;
  const int lane = t & 63;
  const int rid  = t >> 6;                 // 0 .. 3*kBatch-1
  if (rid >= 3 * kBatch) return;
  const int seg = rid / kBatch;
  const int b   = rid - seg * kBatch;
  int idx;
  if (seg == 0)      idx = users[b];
  else if (seg == 1) idx = pos[b] + kNUsers;
  else               idx = neg[b] + kNUsers;
  out[(size_t)rid * 256 + layer * EMB + lane] = cur[(size_t)idx * EMB + lane];
}

// ---------------------------------------------------------------------------
extern "C" void kernel_launch(void* const* d_in, const int* in_sizes, int n_in,
                              void* d_out, int out_size, void* d_ws, size_t ws_size,
                              hipStream_t stream) {
  const int*   users    = (const int*)d_in[0];
  const int*   pos      = (const int*)d_in[1];
  const int*   neg      = (const int*)d_in[2];
  const int*   rows     = (const int*)d_in[3];
  const int*   cols     = (const int*)d_in[4];
  const float* vals     = (const float*)d_in[5];
  const float* user_emb = (const float*)d_in[6];
  const float* item_emb = (const float*)d_in[7];
  const float* W1s      = (const float*)d_in[8];
  const float* b1s      = (const float*)d_in[9];
  const float* W2s      = (const float*)d_in[10];
  const float* b2s      = (const float*)d_in[11];
  float* out = (float*)d_out;

  float* cur  = (float*)d_ws;                         // 150000*64 f32 = 38.4 MB
  float* nbuf = cur + (size_t)kNNodes * EMB;          // 38.4 MB

  hipMemcpyAsync(cur, user_emb, (size_t)kNUsers * EMB * sizeof(float),
                 hipMemcpyDeviceToDevice, stream);
  hipMemcpyAsync(cur + (size_t)kNUsers * EMB, item_emb,
                 (size_t)kNItems * EMB * sizeof(float),
                 hipMemcpyDeviceToDevice, stream);

  const dim3 blk(256);
  const int gblocks = (3 * kBatch * EMB + 255) / 256;             // 12288
  const int sblocks = (((kNEdges + kEPW - 1) / kEPW) + 3) / 4;    // 75000
  const int tblocks = (kNNodes + 255) / 256;                      // 586

  gather_out<<<gblocks, blk, 0, stream>>>(cur, users, pos, neg, out, 0);

  for (int L = 0; L < kLayers; ++L) {
    hipMemsetAsync(nbuf, 0, (size_t)kNNodes * EMB * sizeof(float), stream);
    spmm_atomic<<<sblocks, blk, 0, stream>>>(cur, rows, cols, vals, nbuf);
    transform_inplace<<<tblocks, blk, 0, stream>>>(
        cur, nbuf, W1s + L * EMB * EMB, b1s + L * EMB,
        W2s + L * EMB * EMB, b2s + L * EMB);
    gather_out<<<gblocks, blk, 0, stream>>>(cur, users, pos, neg, out, L + 1);
  }
}

// Round 2
// 1825.752 us; speedup vs baseline: 1.9859x; 1.9859x over previous
//
#include <hip/hip_runtime.h>

// NGCF forward on gfx950 — round 2: CSR-based SpMM (no atomics in the hot path).
//
// Per launch:
//   cur  = concat(user_emb, item_emb)                        [150000 x 64] f32
//   CSR build (graph identical across layers):
//     rowCnt = histogram(rows)          (atomicAdd, 600 KB L2-resident)
//     rowPtr = exclusive_scan(rowCnt)   (single-workgroup scan; zeroes rowCnt)
//     edgeS[rowPtr[r] + ticket] = (col, val)   (atomic ticket scatter)
//   gather layer-0 slice
//   for L in 0..2:
//     spmm_csr: nbuf[r] = sum_e val_e * cur[col_e]   (wave/row, no atomics,
//               no memset — every row written exactly once)
//     transform_inplace: cur = leaky(cur@W1+b1 + t + (t*cur)@W2+b2), t=nbuf@W2+b2
//     gather layer-(L+1) slice
// out = [users | pos | neg] each [16384 x 256] f32.

#define EMB 64

constexpr int kNUsers = 100000;
constexpr int kNItems = 50000;
constexpr int kNNodes = 150000;
constexpr int kNEdges = 4800000;
constexpr int kBatch  = 16384;
constexpr int kLayers = 3;
constexpr int kEPW    = 16;   // edges per wave (fallback atomic spmm only)

__device__ __forceinline__ float f4c(const float4& v, int i) {
  return ((const float*)&v)[i];
}
__device__ __forceinline__ float4 f4fma(float s, float4 w, float4 a) {
  a.x = fmaf(s, w.x, a.x);
  a.y = fmaf(s, w.y, a.y);
  a.z = fmaf(s, w.z, a.z);
  a.w = fmaf(s, w.w, a.w);
  return a;
}
__device__ __forceinline__ float lrelu(float x) { return x > 0.f ? x : 0.2f * x; }

// ---------------------------------------------------------------------------
// CSR build
// ---------------------------------------------------------------------------
__global__ __launch_bounds__(256) void hist_rows(
    const int* __restrict__ rows, int* __restrict__ rowCnt)
{
  const int e = blockIdx.x * 256 + threadIdx.x;
  if (e < kNEdges) atomicAdd(&rowCnt[rows[e]], 1);
}

// Single-workgroup serial-chunk scan: exclusive prefix over 150000 counts.
// Also zeroes rowCnt in-place (reused as the scatter ticket array).
__global__ __launch_bounds__(1024) void scan_rowptr(
    int* __restrict__ rowCnt, int* __restrict__ rowPtr)
{
  __shared__ int wsum[16];
  __shared__ int chunkTotal;
  const int tid  = threadIdx.x;
  const int lane = tid & 63;
  const int wid  = tid >> 6;
  int running = 0;
  for (int base = 0; base < kNNodes; base += 1024) {
    const int i   = base + tid;
    const int cnt = (i < kNNodes) ? rowCnt[i] : 0;
    int v = cnt;                                  // inclusive wave scan
#pragma unroll
    for (int off = 1; off < 64; off <<= 1) {
      int n = __shfl_up(v, off, 64);
      if (lane >= off) v += n;
    }
    if (lane == 63) wsum[wid] = v;
    __syncthreads();
    if (tid == 0) {
      int s = 0;
#pragma unroll
      for (int w = 0; w < 16; ++w) { int t = wsum[w]; wsum[w] = s; s += t; }
      chunkTotal = s;
    }
    __syncthreads();
    const int excl = running + wsum[wid] + v - cnt;
    if (i < kNNodes) { rowPtr[i] = excl; rowCnt[i] = 0; }
    running += chunkTotal;
    __syncthreads();                              // wsum reused next chunk
  }
  if (tid == 0) rowPtr[kNNodes] = running;        // == kNEdges
}

__global__ __launch_bounds__(256) void scatter_edges(
    const int* __restrict__ rows, const int* __restrict__ cols,
    const float* __restrict__ vals, const int* __restrict__ rowPtr,
    int* __restrict__ rowCnt, int2* __restrict__ edgeS)
{
  const int e = blockIdx.x * 256 + threadIdx.x;
  if (e >= kNEdges) return;
  const int r   = rows[e];
  const int idx = rowPtr[r] + atomicAdd(&rowCnt[r], 1);
  edgeS[idx] = make_int2(cols[e], __float_as_int(vals[e]));
}

// ---------------------------------------------------------------------------
// CSR SpMM: one wave per row, lane = dim. No atomics, no memset needed.
// ---------------------------------------------------------------------------
__global__ __launch_bounds__(256) void spmm_csr(
    const float* __restrict__ cur, const int* __restrict__ rowPtr,
    const int2* __restrict__ edgeS, float* __restrict__ nbuf)
{
  const int lane = threadIdx.x & 63;
  const int r = (blockIdx.x << 2) | (threadIdx.x >> 6);
  if (r >= kNNodes) return;
  const int start = __builtin_amdgcn_readfirstlane(rowPtr[r]);
  const int end   = __builtin_amdgcn_readfirstlane(rowPtr[r + 1]);
  float a0 = 0.f, a1 = 0.f;
  int e = start;
  for (; e + 2 <= end; e += 2) {
    const int2 cv0 = edgeS[e];
    const int2 cv1 = edgeS[e + 1];
    a0 = fmaf(__int_as_float(cv0.y), cur[(size_t)cv0.x * EMB + lane], a0);
    a1 = fmaf(__int_as_float(cv1.y), cur[(size_t)cv1.x * EMB + lane], a1);
  }
  if (e < end) {
    const int2 cv = edgeS[e];
    a0 = fmaf(__int_as_float(cv.y), cur[(size_t)cv.x * EMB + lane], a0);
  }
  nbuf[(size_t)r * EMB + lane] = a0 + a1;
}

// ---------------------------------------------------------------------------
// Fallback atomic SpMM (only used if ws_size too small for CSR buffers).
// ---------------------------------------------------------------------------
__global__ __launch_bounds__(256) void spmm_atomic(
    const float* __restrict__ cur, const int* __restrict__ rows,
    const int* __restrict__ cols, const float* __restrict__ vals,
    float* __restrict__ nbuf)
{
  const int lane = threadIdx.x & 63;
  int wv = (blockIdx.x << 2) | (threadIdx.x >> 6);
  wv = __builtin_amdgcn_readfirstlane(wv);
  int e0 = wv * kEPW;
  int e1 = e0 + kEPW;
  if (e1 > kNEdges) e1 = kNEdges;
  for (int e = e0; e < e1; ++e) {
    const int   c = cols[e];
    const int   r = rows[e];
    const float v = vals[e];
    atomicAdd(nbuf + (size_t)r * EMB + lane, v * cur[(size_t)c * EMB + lane]);
  }
}

// ---------------------------------------------------------------------------
// Fused per-node transform (unchanged from R1; ~25 µs/layer, VALU-bound).
// ---------------------------------------------------------------------------
__global__ __launch_bounds__(256) void transform_inplace(
    float* __restrict__ cur, const float* __restrict__ nbuf,
    const float* __restrict__ W1, const float* __restrict__ b1,
    const float* __restrict__ W2, const float* __restrict__ b2)
{
  const int node = blockIdx.x * 256 + threadIdx.x;
  if (node >= kNNodes) return;

  const float4* __restrict__ xr  = (const float4*)(cur  + (size_t)node * EMB);
  const float4* __restrict__ nr  = (const float4*)(nbuf + (size_t)node * EMB);
  const float4* __restrict__ b1v = (const float4*)b1;
  const float4* __restrict__ b2v = (const float4*)b2;

  float4 acc1[16], acc2[16];
#pragma unroll
  for (int j = 0; j < 16; ++j) { acc1[j] = b1v[j]; acc2[j] = b2v[j]; }

#pragma unroll 2
  for (int k4 = 0; k4 < 16; ++k4) {
    const float4 xv = xr[k4];
    const float4 nv = nr[k4];
#pragma unroll
    for (int kk = 0; kk < 4; ++kk) {
      const int k = 4 * k4 + kk;
      const float xs = f4c(xv, kk);
      const float ns = f4c(nv, kk);
      const float4* __restrict__ w1r = (const float4*)(W1 + k * EMB);
      const float4* __restrict__ w2r = (const float4*)(W2 + k * EMB);
#pragma unroll
      for (int j = 0; j < 16; ++j) {
        acc1[j] = f4fma(xs, w1r[j], acc1[j]);
        acc2[j] = f4fma(ns, w2r[j], acc2[j]);
      }
    }
  }

#pragma unroll
  for (int k4 = 0; k4 < 16; ++k4) {
    const float4 xv = xr[k4];
    const float4 tv = acc2[k4];
#pragma unroll
    for (int kk = 0; kk < 4; ++kk) {
      const float ms = f4c(tv, kk) * f4c(xv, kk);
      const float4* __restrict__ w2r = (const float4*)(W2 + (4 * k4 + kk) * EMB);
#pragma unroll
      for (int j = 0; j < 16; ++j) acc1[j] = f4fma(ms, w2r[j], acc1[j]);
    }
  }

  float4* __restrict__ outp = (float4*)(cur + (size_t)node * EMB);
#pragma unroll
  for (int j = 0; j < 16; ++j) {
    float4 r;
    r.x = lrelu(acc1[j].x + acc2[j].x + b2v[j].x);
    r.y = lrelu(acc1[j].y + acc2[j].y + b2v[j].y);
    r.z = lrelu(acc1[j].z + acc2[j].z + b2v[j].z);
    r.w = lrelu(acc1[j].w + acc2[j].w + b2v[j].w);
    outp[j] = r;
  }
}

// ---------------------------------------------------------------------------
__global__ __launch_bounds__(256) void gather_out(
    const float* __restrict__ cur, const int* __restrict__ users,
    const int* __restrict__ pos, const int* __restrict__ neg,
    float* __restrict__ out, int layer)
{
  const int t    = blockIdx.x * 256 + threadIdx.x;
  const int lane = t & 63;
  const int rid  = t >> 6;
  if (rid >= 3 * kBatch) return;
  const int seg = rid / kBatch;
  const int b   = rid - seg * kBatch;
  int idx;
  if (seg == 0)      idx = users[b];
  else if (seg == 1) idx = pos[b] + kNUsers;
  else               idx = neg[b] + kNUsers;
  out[(size_t)rid * 256 + layer * EMB + lane] = cur[(size_t)idx * EMB + lane];
}

// ---------------------------------------------------------------------------
extern "C" void kernel_launch(void* const* d_in, const int* in_sizes, int n_in,
                              void* d_out, int out_size, void* d_ws, size_t ws_size,
                              hipStream_t stream) {
  const int*   users    = (const int*)d_in[0];
  const int*   pos      = (const int*)d_in[1];
  const int*   neg      = (const int*)d_in[2];
  const int*   rows     = (const int*)d_in[3];
  const int*   cols     = (const int*)d_in[4];
  const float* vals     = (const float*)d_in[5];
  const float* user_emb = (const float*)d_in[6];
  const float* item_emb = (const float*)d_in[7];
  const float* W1s      = (const float*)d_in[8];
  const float* b1s      = (const float*)d_in[9];
  const float* W2s      = (const float*)d_in[10];
  const float* b2s      = (const float*)d_in[11];
  float* out = (float*)d_out;

  // ws layout
  const size_t nodeF   = (size_t)kNNodes * EMB;              // 9.6M floats
  float* cur  = (float*)d_ws;                                // 38.4 MB
  float* nbuf = cur + nodeF;                                 // 38.4 MB
  int2*  edgeS  = (int2*)(nbuf + nodeF);                     // 38.4 MB
  int*   rowPtr = (int*)(edgeS + kNEdges);                   // 600 KB (+1)
  int*   rowCnt = rowPtr + (kNNodes + 1);                    // 600 KB
  const size_t needed = (size_t)(rowCnt + kNNodes) - (size_t)d_ws;
  const bool useCsr = ws_size >= needed;

  hipMemcpyAsync(cur, user_emb, (size_t)kNUsers * EMB * sizeof(float),
                 hipMemcpyDeviceToDevice, stream);
  hipMemcpyAsync(cur + (size_t)kNUsers * EMB, item_emb,
                 (size_t)kNItems * EMB * sizeof(float),
                 hipMemcpyDeviceToDevice, stream);

  const dim3 blk(256);
  const int gblocks = (3 * kBatch * EMB + 255) / 256;             // 12288
  const int eblocks = (kNEdges + 255) / 256;                      // 18750
  const int rblocks = (kNNodes + 3) / 4;                          // 37500
  const int tblocks = (kNNodes + 255) / 256;                      // 586

  if (useCsr) {
    hipMemsetAsync(rowCnt, 0, (size_t)kNNodes * sizeof(int), stream);
    hist_rows<<<eblocks, blk, 0, stream>>>(rows, rowCnt);
    scan_rowptr<<<1, 1024, 0, stream>>>(rowCnt, rowPtr);
    scatter_edges<<<eblocks, blk, 0, stream>>>(rows, cols, vals, rowPtr,
                                               rowCnt, edgeS);
  }

  gather_out<<<gblocks, blk, 0, stream>>>(cur, users, pos, neg, out, 0);

  for (int L = 0; L < kLayers; ++L) {
    if (useCsr) {
      spmm_csr<<<rblocks, blk, 0, stream>>>(cur, rowPtr, edgeS, nbuf);
    } else {
      hipMemsetAsync(nbuf, 0, nodeF * sizeof(float), stream);
      const int sblocks = (((kNEdges + kEPW - 1) / kEPW) + 3) / 4;
      spmm_atomic<<<sblocks, blk, 0, stream>>>(cur, rows, cols, vals, nbuf);
    }
    transform_inplace<<<tblocks, blk, 0, stream>>>(
        cur, nbuf, W1s + L * EMB * EMB, b1s + L * EMB,
        W2s + L * EMB * EMB, b2s + L * EMB);
    gather_out<<<gblocks, blk, 0, stream>>>(cur, users, pos, neg, out, L + 1);
  }
}